// Round 9
// baseline (742.663 us; speedup 1.0000x reference)
//
#include <hip/hip_runtime.h>
#include <math.h>

#define SS 65536               // F*T
#define PLANE 4194304          // CC*SS floats per (b,part)
#define TEN_ELEMS 16777216     // 2*2*CC*SS floats per tensor
#define NSAMP 131072.0f        // B*F*T samples per BN channel

typedef __bf16 bf16x8 __attribute__((ext_vector_type(8)));
typedef __bf16 bf16x4v __attribute__((ext_vector_type(4)));
typedef float  f32x4  __attribute__((ext_vector_type(4)));

__device__ inline f32x4 mfma16(bf16x8 a, bf16x8 b, f32x4 c) {
  return __builtin_amdgcn_mfma_f32_16x16x32_bf16(a, b, c, 0, 0, 0);
}
__device__ inline bf16x8 neg8(bf16x8 v) {
  union { bf16x8 b; unsigned u[4]; } t; t.b = v;
#pragma unroll
  for (int i = 0; i < 4; ++i) t.u[i] ^= 0x80008000u;
  return t.b;
}
__device__ inline float bnlrelu(float v, float sc, float sh) {
  float t = fmaf(v, sc, sh);
  return t > 0.f ? t : 0.01f * t;
}

// swizzled element offset of 16B-granule g within row r (rows of 40 elems)
__device__ inline int swz(int r, int g) {
  return r * 40 + (((g ^ (r >> 2) ^ (r >> 4)) & 3) << 3);
}

// ======== input covariance + mean partials: Cwin = Xwin Xwin^T ==============
__global__ __launch_bounds__(256) void stats_cov(
    const float* __restrict__ xQ, const float* __restrict__ xP,
    float* __restrict__ cpart, float* __restrict__ mbuck)
{
  __shared__ __align__(16) __bf16 sXh[128 * 72];
  __shared__ __align__(16) __bf16 sXl[128 * 72];
  const int tid = threadIdx.x;
  const int win = blockIdx.x;             // 0..255 (256-s windows)
  const int tz = blockIdx.y;              // 0=Q, 1=P
  const float* x = tz ? xP : xQ;
  const int w = tid >> 6, q = (tid >> 4) & 3, ln = tid & 15;
  const int pcb = tid >> 4;               // row group owner (16 s-lanes each)
  const int s4 = (tid & 15) * 4;

  f32x4 zero = {0.f, 0.f, 0.f, 0.f};
  f32x4 acc[2][8];
#pragma unroll
  for (int mt = 0; mt < 2; ++mt)
#pragma unroll
    for (int nt = 0; nt < 8; ++nt) acc[mt][nt] = zero;
  float msum[8] = {0.f, 0.f, 0.f, 0.f, 0.f, 0.f, 0.f, 0.f};

  for (int half = 0; half < 8; ++half) {
    const int bb = half >> 2;
    const int sbase = win * 256 + (half & 3) * 64;
#pragma unroll
    for (int r = 0; r < 8; ++r) {
      int pc = pcb + r * 16;
      float4 v4 = *(const float4*)&x[(size_t)(bb * 128 + pc) * SS + sbase + s4];
      msum[r] += v4.x + v4.y + v4.z + v4.w;
      float vv[4] = {v4.x, v4.y, v4.z, v4.w};
      bf16x4v hv, lv;
#pragma unroll
      for (int e = 0; e < 4; ++e) {
        __bf16 h = (__bf16)vv[e];
        hv[e] = h; lv[e] = (__bf16)(vv[e] - (float)h);
      }
      *(bf16x4v*)&sXh[pc * 72 + s4] = hv;
      *(bf16x4v*)&sXl[pc * 72 + s4] = lv;
    }
    __syncthreads();
#pragma unroll
    for (int ks = 0; ks < 2; ++ks) {
      bf16x8 ah[2], al[2];
#pragma unroll
      for (int mt = 0; mt < 2; ++mt) {
        int ra = w * 32 + mt * 16 + ln;
        ah[mt] = *(const bf16x8*)&sXh[ra * 72 + ks * 32 + q * 8];
        al[mt] = *(const bf16x8*)&sXl[ra * 72 + ks * 32 + q * 8];
      }
#pragma unroll
      for (int nt = 0; nt < 8; ++nt) {
        int rb = nt * 16 + ln;
        bf16x8 bh = *(const bf16x8*)&sXh[rb * 72 + ks * 32 + q * 8];
        bf16x8 bl = *(const bf16x8*)&sXl[rb * 72 + ks * 32 + q * 8];
#pragma unroll
        for (int mt = 0; mt < 2; ++mt) {
          f32x4 a = acc[mt][nt];
          a = mfma16(ah[mt], bh, a);
          a = mfma16(ah[mt], bl, a);
          a = mfma16(al[mt], bh, a);
          acc[mt][nt] = a;
        }
      }
    }
    __syncthreads();
  }
#pragma unroll
  for (int r = 0; r < 8; ++r) {
    float v = msum[r];
#pragma unroll
    for (int off = 1; off < 16; off <<= 1) v += __shfl_xor(v, off, 64);
    if (ln == 0)
      atomicAdd(&mbuck[((win & 63) * 2 + tz) * 128 + pcb + r * 16], v);
  }
  float* cp = cpart + ((size_t)tz * 256 + win) * 16384;
#pragma unroll
  for (int mt = 0; mt < 2; ++mt)
#pragma unroll
    for (int nt = 0; nt < 8; ++nt)
#pragma unroll
      for (int r = 0; r < 4; ++r) {
        int row = w * 32 + mt * 16 + q * 4 + r;
        int col = nt * 16 + ln;
        cp[row * 128 + col] = acc[mt][nt][r];
      }
}

// ======== reduce window partials ============================================
__global__ __launch_bounds__(256) void cov_reduce(
    const float* __restrict__ cpart, const float* __restrict__ mbuck,
    float* __restrict__ csum, float* __restrict__ msum)
{
  int i = blockIdx.x * 256 + threadIdx.x;   // 0..32767
  int tz = i >> 14, e = i & 16383;
  const float* p = cpart + (size_t)tz * 256 * 16384 + e;
  float s = 0.f;
#pragma unroll 4
  for (int k = 0; k < 256; ++k) s += p[(size_t)k * 16384];
  csum[i] = s;
  if (i < 256) {
    int t2 = i >> 7, row = i & 127;
    float sm2 = 0.f;
#pragma unroll 4
    for (int k = 0; k < 64; ++k) sm2 += mbuck[(k * 2 + t2) * 128 + row];
    msum[i] = sm2;
  }
}

// ======== BN scale/shift from covariance ====================================
__global__ void bn_precompute(
    const float* __restrict__ Cq, const float* __restrict__ Cp,
    const float* __restrict__ mq, const float* __restrict__ mp,
    const float* __restrict__ W, const float* __restrict__ g,
    const float* __restrict__ beta,
    float* __restrict__ scale6, float* __restrict__ shift6)
{
  const int rr = blockIdx.x >> 7;       // role 0..5
  const int o  = blockIdx.x & 127;      // output pc
  const int i  = threadIdx.x;           // input pc 0..127
  const float* C = (rr % 3 == 0) ? Cq : Cp;
  const float* m = (rr % 3 == 0) ? mq : mp;
  const int po = o >> 6, co = o & 63;
  const int pi = i >> 6, ci = i & 63;
  float wv = W[rr * 8192 + ((po ^ pi) << 12) + co * 64 + ci];
  if (po == 0 && pi == 1) wv = -wv;
  __shared__ float sW[128];
  sW[i] = wv;
  __syncthreads();
  float t = 0.f;
  const float* crow = C + i * 128;
#pragma unroll 8
  for (int j = 0; j < 128; ++j) t += crow[j] * sW[j];
  float pv = wv * t;
  float pm = wv * m[i];
#pragma unroll
  for (int off = 1; off < 64; off <<= 1) {
    pv += __shfl_xor(pv, off, 64);
    pm += __shfl_xor(pm, off, 64);
  }
  __shared__ float red[4];
  if ((i & 63) == 0) { red[(i >> 6) * 2] = pv; red[(i >> 6) * 2 + 1] = pm; }
  __syncthreads();
  if (i == 0) {
    float v = red[0] + red[2];
    float wm = red[1] + red[3];
    float muT = wm / NSAMP;
    float var = v / NSAMP - muT * muT;
    float sc = g[rr * 128 + o] * rsqrtf(var + 1e-5f);
    scale6[rr * 128 + o] = sc;
    shift6[rr * 128 + o] = beta[rr * 128 + o] - muT * sc;
  }
}

// ============ Q conv: 1x1 complex conv + BN/leaky -> grouped-packed =========
__global__ __launch_bounds__(256) void cconv_mfma(
    const float* __restrict__ x, const float* __restrict__ Wj,
    const float* __restrict__ scale, const float* __restrict__ shiftp,
    void* __restrict__ outA, int freq)
{
  __shared__ __align__(16) char smemBlk[34816];
  __bf16* sBh = (__bf16*)smemBlk;               // [64 s][136 pc]
  __bf16* sBl = (__bf16*)(smemBlk + 17408);
  const int tid = threadIdx.x;
  const int b = blockIdx.y;
  const int s0 = blockIdx.x << 6;
  const int w = tid >> 6, q = (tid >> 4) & 3, ln = tid & 15;

  bf16x8 ah[2][4], al[2][4];
#pragma unroll
  for (int mt = 0; mt < 2; ++mt) {
    int row = w * 32 + mt * 16 + ln;
    int po = row >> 6, co = row & 63;
#pragma unroll
    for (int ks = 0; ks < 4; ++ks) {
      bf16x8 vh, vl;
#pragma unroll
      for (int j = 0; j < 8; ++j) {
        int k = ks * 32 + q * 8 + j;
        int pi = k >> 6, c = k & 63;
        float v = Wj[((po ^ pi) << 12) + co * 64 + c];
        if (po == 0 && pi == 1) v = -v;
        __bf16 h = (__bf16)v;
        vh[j] = h;
        vl[j] = (__bf16)(v - (float)h);
      }
      ah[mt][ks] = vh; al[mt][ks] = vl;
    }
  }

#pragma unroll
  for (int ph = 0; ph < 2; ++ph) {
    int pc = ph * 64 + (tid & 63);
    const float* rowp = x + (size_t)(b * 128 + pc) * SS + s0;
#pragma unroll
    for (int sh2 = 0; sh2 < 2; ++sh2)
#pragma unroll
      for (int sc2 = 0; sc2 < 2; ++sc2) {
        int sl = ((tid >> 6) << 3) + sh2 * 32 + sc2 * 4;
        float4 rd = *(const float4*)&rowp[sl];
        float vv[4] = {rd.x, rd.y, rd.z, rd.w};
#pragma unroll
        for (int e = 0; e < 4; ++e) {
          __bf16 h = (__bf16)vv[e];
          sBh[(sl + e) * 136 + pc] = h;
          sBl[(sl + e) * 136 + pc] = (__bf16)(vv[e] - (float)h);
        }
      }
  }
  __syncthreads();

  f32x4 zero = {0.f, 0.f, 0.f, 0.f};
  f32x4 acc[2][4];
#pragma unroll
  for (int mt = 0; mt < 2; ++mt)
#pragma unroll
    for (int nt = 0; nt < 4; ++nt) acc[mt][nt] = zero;

#pragma unroll
  for (int ks = 0; ks < 4; ++ks) {
    bf16x8 bh[4], bl[4];
#pragma unroll
    for (int nt = 0; nt < 4; ++nt) {
      int off = (nt * 16 + ln) * 136 + ks * 32 + q * 8;
      bh[nt] = *(const bf16x8*)&sBh[off];
      bl[nt] = *(const bf16x8*)&sBl[off];
    }
#pragma unroll
    for (int mt = 0; mt < 2; ++mt)
#pragma unroll
      for (int nt = 0; nt < 4; ++nt) {
        acc[mt][nt] = mfma16(ah[mt][ks], bh[nt], acc[mt][nt]);
        acc[mt][nt] = mfma16(ah[mt][ks], bl[nt], acc[mt][nt]);
        acc[mt][nt] = mfma16(al[mt][ks], bh[nt], acc[mt][nt]);
      }
  }

  float scv[2][4], shv[2][4];
#pragma unroll
  for (int mt = 0; mt < 2; ++mt)
#pragma unroll
    for (int r = 0; r < 4; ++r) {
      int row = w * 32 + mt * 16 + q * 4 + r;
      scv[mt][r] = scale[row];
      shv[mt][r] = shiftp[row];
    }

  // grouped-packed epilogue (LDS transpose)
  __syncthreads();
  float* sT = (float*)smemBlk;     // [64 t][133]
#pragma unroll
  for (int mt = 0; mt < 2; ++mt)
#pragma unroll
    for (int nt = 0; nt < 4; ++nt)
#pragma unroll
      for (int r = 0; r < 4; ++r)
        sT[(nt * 16 + ln) * 133 + (w * 32 + mt * 16 + q * 4 + r)] =
            bnlrelu(acc[mt][nt][r], scv[mt][r], shv[mt][r]);
  __syncthreads();
  const int pch = tid >> 6, tl = tid & 63;
  float vv[32];
#pragma unroll
  for (int j2 = 0; j2 < 8; ++j2)
    *(f32x4*)&vv[j2 * 4] = *(const f32x4*)&sT[tl * 133 + pch * 32 + j2 * 4];
  bf16x8 hh[4], ll[4];
#pragma unroll
  for (int j2 = 0; j2 < 4; ++j2)
#pragma unroll
    for (int e = 0; e < 8; ++e) {
      float v = vv[j2 * 8 + e];
      __bf16 h = (__bf16)v;
      hh[j2][e] = h; ll[j2][e] = (__bf16)(v - (float)h);
    }
  __bf16* out = (__bf16*)outA;
  if (!freq) {
    const int p = pch >> 1, ch2 = pch & 1;
    int chunk = (s0 >> 8) * 2 + ch2;
    int tok = (s0 & 255) + tl;
    size_t a = (size_t)(b * 2 + p) * (2 * (size_t)PLANE) +
               ((size_t)chunk * 256 + tok) * 64;
#pragma unroll
    for (int j2 = 0; j2 < 4; ++j2) {
      *(bf16x8*)&out[a + j2 * 8]      = hh[j2];
      *(bf16x8*)&out[a + 32 + j2 * 8] = ll[j2];
    }
  } else {
    __syncthreads();
    __bf16* sP = (__bf16*)smemBlk;   // [256 groups][64]
    __bf16* me = sP + tid * 64;
#pragma unroll
    for (int j2 = 0; j2 < 4; ++j2) {
      *(bf16x8*)&me[j2 * 8]      = hh[j2];
      *(bf16x8*)&me[32 + j2 * 8] = ll[j2];
    }
    __syncthreads();
#pragma unroll
    for (int r2 = 0; r2 < 8; ++r2) {
      int u = tid + (r2 << 8);
      int g2 = u >> 3, piece = u & 7;
      int pch2 = g2 >> 6, t2 = g2 & 63;
      int chunk = ((s0 & 255) + t2) * 2 + (pch2 & 1);
      int tok = s0 >> 8;
      size_t a = (size_t)(b * 2 + (pch2 >> 1)) * (2 * (size_t)PLANE) +
                 ((size_t)chunk * 256 + tok) * 64 + piece * 8;
      *(bf16x8*)&out[a] = *(const bf16x8*)&sP[(size_t)u * 8];
    }
  }
}

// ============ fused K+V conv: stage P once, two weight passes ===============
// K -> grouped-packed (outK). V: time -> packed rows (outVa/outVb bf16);
// freq -> post-BN f32 (outVa).
__global__ __launch_bounds__(256) void cconv_kv(
    const float* __restrict__ x,
    const float* __restrict__ Wk, const float* __restrict__ Wv,
    const float* __restrict__ scK, const float* __restrict__ shK,
    const float* __restrict__ scV, const float* __restrict__ shV,
    void* __restrict__ outK, void* __restrict__ outVa,
    void* __restrict__ outVb, int freq)
{
  __shared__ __align__(16) char smemBlk[34816];
  __bf16* sBh = (__bf16*)smemBlk;               // [64 s][136 pc]
  __bf16* sBl = (__bf16*)(smemBlk + 17408);
  const int tid = threadIdx.x;
  const int b = blockIdx.y;
  const int s0 = blockIdx.x << 6;
  const int w = tid >> 6, q = (tid >> 4) & 3, ln = tid & 15;

  // stage input once
#pragma unroll
  for (int ph = 0; ph < 2; ++ph) {
    int pc = ph * 64 + (tid & 63);
    const float* rowp = x + (size_t)(b * 128 + pc) * SS + s0;
#pragma unroll
    for (int sh2 = 0; sh2 < 2; ++sh2)
#pragma unroll
      for (int sc2 = 0; sc2 < 2; ++sc2) {
        int sl = ((tid >> 6) << 3) + sh2 * 32 + sc2 * 4;
        float4 rd = *(const float4*)&rowp[sl];
        float vv[4] = {rd.x, rd.y, rd.z, rd.w};
#pragma unroll
        for (int e = 0; e < 4; ++e) {
          __bf16 h = (__bf16)vv[e];
          sBh[(sl + e) * 136 + pc] = h;
          sBl[(sl + e) * 136 + pc] = (__bf16)(vv[e] - (float)h);
        }
      }
  }
  __syncthreads();

  f32x4 zero = {0.f, 0.f, 0.f, 0.f};
  f32x4 accKV[2][2][4];
#pragma unroll
  for (int role = 0; role < 2; ++role)
#pragma unroll
    for (int mt = 0; mt < 2; ++mt)
#pragma unroll
      for (int nt = 0; nt < 4; ++nt) accKV[role][mt][nt] = zero;

  for (int role = 0; role < 2; ++role) {
    const float* Wj = role ? Wv : Wk;
    bf16x8 ah[2][4], al[2][4];
#pragma unroll
    for (int mt = 0; mt < 2; ++mt) {
      int row = w * 32 + mt * 16 + ln;
      int po = row >> 6, co = row & 63;
#pragma unroll
      for (int ks = 0; ks < 4; ++ks) {
        bf16x8 vh, vl;
#pragma unroll
        for (int j = 0; j < 8; ++j) {
          int k = ks * 32 + q * 8 + j;
          int pi = k >> 6, c = k & 63;
          float v = Wj[((po ^ pi) << 12) + co * 64 + c];
          if (po == 0 && pi == 1) v = -v;
          __bf16 h = (__bf16)v;
          vh[j] = h;
          vl[j] = (__bf16)(v - (float)h);
        }
        ah[mt][ks] = vh; al[mt][ks] = vl;
      }
    }
#pragma unroll
    for (int ks = 0; ks < 4; ++ks) {
      bf16x8 bh[4], bl[4];
#pragma unroll
      for (int nt = 0; nt < 4; ++nt) {
        int off = (nt * 16 + ln) * 136 + ks * 32 + q * 8;
        bh[nt] = *(const bf16x8*)&sBh[off];
        bl[nt] = *(const bf16x8*)&sBl[off];
      }
#pragma unroll
      for (int mt = 0; mt < 2; ++mt)
#pragma unroll
        for (int nt = 0; nt < 4; ++nt) {
          f32x4 a = accKV[role][mt][nt];
          a = mfma16(ah[mt][ks], bh[nt], a);
          a = mfma16(ah[mt][ks], bl[nt], a);
          a = mfma16(al[mt][ks], bh[nt], a);
          accKV[role][mt][nt] = a;
        }
    }
  }

  // BN params
  float scvK[2][4], shvK[2][4], scvV[2][4], shvV[2][4];
#pragma unroll
  for (int mt = 0; mt < 2; ++mt)
#pragma unroll
    for (int r = 0; r < 4; ++r) {
      int row = w * 32 + mt * 16 + q * 4 + r;
      scvK[mt][r] = scK[row]; shvK[mt][r] = shK[row];
      scvV[mt][r] = scV[row]; shvV[mt][r] = shV[row];
    }

  // ---- V epilogue (no LDS) ----
  if (!freq) {
    __bf16* vh = (__bf16*)outVa;
    __bf16* vl = (__bf16*)outVb;
    const int f = s0 >> 8, t0 = s0 & 255;
#pragma unroll
    for (int mt = 0; mt < 2; ++mt)
#pragma unroll
      for (int r = 0; r < 4; ++r) {
        int row = w * 32 + mt * 16 + q * 4 + r;
        int p = row >> 6, c = row & 63;
        size_t rbase = ((size_t)((b * 2 + p) * 16384 + c * 256 + f)) * 256 + t0;
#pragma unroll
        for (int nt = 0; nt < 4; ++nt) {
          float v = bnlrelu(accKV[1][mt][nt][r], scvV[mt][r], shvV[mt][r]);
          __bf16 h = (__bf16)v;
          vh[rbase + nt * 16 + ln] = h;
          vl[rbase + nt * 16 + ln] = (__bf16)(v - (float)h);
        }
      }
  } else {
    float* y = (float*)outVa;
#pragma unroll
    for (int mt = 0; mt < 2; ++mt)
#pragma unroll
      for (int r = 0; r < 4; ++r) {
        int row = w * 32 + mt * 16 + q * 4 + r;
#pragma unroll
        for (int nt = 0; nt < 4; ++nt)
          y[(size_t)(b * 128 + row) * SS + s0 + nt * 16 + ln] =
              bnlrelu(accKV[1][mt][nt][r], scvV[mt][r], shvV[mt][r]);
      }
  }

  // ---- K grouped-packed epilogue (LDS scratch after barrier) ----
  __syncthreads();
  float* sT = (float*)smemBlk;     // [64 t][133]
#pragma unroll
  for (int mt = 0; mt < 2; ++mt)
#pragma unroll
    for (int nt = 0; nt < 4; ++nt)
#pragma unroll
      for (int r = 0; r < 4; ++r)
        sT[(nt * 16 + ln) * 133 + (w * 32 + mt * 16 + q * 4 + r)] =
            bnlrelu(accKV[0][mt][nt][r], scvK[mt][r], shvK[mt][r]);
  __syncthreads();
  const int pch = tid >> 6, tl = tid & 63;
  float vv[32];
#pragma unroll
  for (int j2 = 0; j2 < 8; ++j2)
    *(f32x4*)&vv[j2 * 4] = *(const f32x4*)&sT[tl * 133 + pch * 32 + j2 * 4];
  bf16x8 hh[4], ll[4];
#pragma unroll
  for (int j2 = 0; j2 < 4; ++j2)
#pragma unroll
    for (int e = 0; e < 8; ++e) {
      float v = vv[j2 * 8 + e];
      __bf16 h = (__bf16)v;
      hh[j2][e] = h; ll[j2][e] = (__bf16)(v - (float)h);
    }
  __bf16* out = (__bf16*)outK;
  if (!freq) {
    const int p = pch >> 1, ch2 = pch & 1;
    int chunk = (s0 >> 8) * 2 + ch2;
    int tok = (s0 & 255) + tl;
    size_t a = (size_t)(b * 2 + p) * (2 * (size_t)PLANE) +
               ((size_t)chunk * 256 + tok) * 64;
#pragma unroll
    for (int j2 = 0; j2 < 4; ++j2) {
      *(bf16x8*)&out[a + j2 * 8]      = hh[j2];
      *(bf16x8*)&out[a + 32 + j2 * 8] = ll[j2];
    }
  } else {
    __syncthreads();
    __bf16* sP = (__bf16*)smemBlk;   // [256 groups][64]
    __bf16* me = sP + tid * 64;
#pragma unroll
    for (int j2 = 0; j2 < 4; ++j2) {
      *(bf16x8*)&me[j2 * 8]      = hh[j2];
      *(bf16x8*)&me[32 + j2 * 8] = ll[j2];
    }
    __syncthreads();
#pragma unroll
    for (int r2 = 0; r2 < 8; ++r2) {
      int u = tid + (r2 << 8);
      int g2 = u >> 3, piece = u & 7;
      int pch2 = g2 >> 6, t2 = g2 & 63;
      int chunk = ((s0 & 255) + t2) * 2 + (pch2 & 1);
      int tok = s0 >> 8;
      size_t a = (size_t)(b * 2 + (pch2 >> 1)) * (2 * (size_t)PLANE) +
                 ((size_t)chunk * 256 + tok) * 64 + piece * 8;
      *(bf16x8*)&out[a] = *(const bf16x8*)&sP[(size_t)u * 8];
    }
  }
}

// ============ complex scores: register-prefetched staging ===================
__global__ __launch_bounds__(256) void score_mfma(
    const __bf16* __restrict__ qt, const __bf16* __restrict__ kt,
    float* __restrict__ SR, float* __restrict__ SI)
{
  __shared__ __align__(16) __bf16 sQh[2 * 128 * 40], sQl[2 * 128 * 40];
  __shared__ __align__(16) __bf16 sKh[2 * 64 * 40],  sKl[2 * 64 * 40];
  const int tid = threadIdx.x;
  const int sid = blockIdx.x + (blockIdx.y << 3) + (blockIdx.z << 8);
  const int kk = sid & 7, tt = sid >> 3;
  const int n0 = (kk & 1) << 7;
  const int b  = (kk >> 1) & 1;
  const int m0 = (tt & 3) << 6;
  const int g0 = (((kk >> 2) << 4) + (tt >> 2)) << 4;   // 32 splits x 16 chunks
  const int w = tid >> 6, q4 = (tid >> 4) & 3, ln = tid & 15;
  const size_t pb = (size_t)(b * 2) * (2 * (size_t)PLANE);

  // chunk-invariant load addresses (chunk stride = 16384 elems) and LDS dsts
  size_t aq[4], ak[2];
  int dq[4], dk[2];
#pragma unroll
  for (int r = 0; r < 4; ++r) {
    int u = tid + (r << 8);
    int g_ = u & 3, tok = (u >> 2) & 127, p = u >> 9;
    aq[r] = pb + (size_t)p * (2 * (size_t)PLANE) +
            (size_t)(g0 * 256 + n0 + tok) * 64 + (g_ << 3);
    dq[r] = swz(p * 128 + tok, g_);
  }
#pragma unroll
  for (int r = 0; r < 2; ++r) {
    int u = tid + (r << 8);
    int g_ = u & 3, tok = (u >> 2) & 63, p = u >> 8;
    ak[r] = pb + (size_t)p * (2 * (size_t)PLANE) +
            (size_t)(g0 * 256 + m0 + tok) * 64 + (g_ << 3);
    dk[r] = swz(p * 64 + tok, g_);
  }

  f32x4 zero = {0.f, 0.f, 0.f, 0.f};
  f32x4 accr[2][4], acci[2][4];
#pragma unroll
  for (int st = 0; st < 2; ++st)
#pragma unroll
    for (int mt = 0; mt < 4; ++mt) { accr[st][mt] = zero; acci[st][mt] = zero; }

  // prologue: chunk 0 into registers
  bf16x8 pqh[4], pql[4], pkh[2], pkl[2];
#pragma unroll
  for (int r = 0; r < 4; ++r) {
    pqh[r] = *(const bf16x8*)&qt[aq[r]];
    pql[r] = *(const bf16x8*)&qt[aq[r] + 32];
  }
#pragma unroll
  for (int r = 0; r < 2; ++r) {
    pkh[r] = *(const bf16x8*)&kt[ak[r]];
    pkl[r] = *(const bf16x8*)&kt[ak[r] + 32];
  }

  for (int ch = 0; ch < 16; ++ch) {
    // write staged regs to LDS
#pragma unroll
    for (int r = 0; r < 4; ++r) {
      *(bf16x8*)&sQh[dq[r]] = pqh[r];
      *(bf16x8*)&sQl[dq[r]] = pql[r];
    }
#pragma unroll
    for (int r = 0; r < 2; ++r) {
      *(bf16x8*)&sKh[dk[r]] = pkh[r];
      *(bf16x8*)&sKl[dk[r]] = pkl[r];
    }
    // prefetch next chunk (hides under this chunk's MFMA)
    if (ch < 15) {
      size_t d = (size_t)(ch + 1) * 16384;
#pragma unroll
      for (int r = 0; r < 4; ++r) {
        pqh[r] = *(const bf16x8*)&qt[aq[r] + d];
        pql[r] = *(const bf16x8*)&qt[aq[r] + d + 32];
      }
#pragma unroll
      for (int r = 0; r < 2; ++r) {
        pkh[r] = *(const bf16x8*)&kt[ak[r] + d];
        pkl[r] = *(const bf16x8*)&kt[ak[r] + d + 32];
      }
    }
    __syncthreads();

    bf16x8 qh[2][2], ql2[2][2], nqh[2], nql[2];
#pragma unroll
    for (int st = 0; st < 2; ++st) {
      int tokn = w * 32 + st * 16 + ln;
#pragma unroll
      for (int p = 0; p < 2; ++p) {
        int off = swz(p * 128 + tokn, q4);
        qh[st][p]  = *(const bf16x8*)&sQh[off];
        ql2[st][p] = *(const bf16x8*)&sQl[off];
      }
      nqh[st] = neg8(qh[st][0]);
      nql[st] = neg8(ql2[st][0]);
    }
#pragma unroll
    for (int mt = 0; mt < 4; ++mt) {
      int tk = mt * 16 + ln;
      int offr = swz(tk, q4), offi = swz(64 + tk, q4);
      bf16x8 krh = *(const bf16x8*)&sKh[offr];
      bf16x8 krl = *(const bf16x8*)&sKl[offr];
      bf16x8 kih = *(const bf16x8*)&sKh[offi];
      bf16x8 kil = *(const bf16x8*)&sKl[offi];
#pragma unroll
      for (int st = 0; st < 2; ++st) {
        f32x4 ar = accr[st][mt], ai = acci[st][mt];
        ar = mfma16(qh[st][0], krh, ar);
        ar = mfma16(qh[st][0], krl, ar);
        ar = mfma16(ql2[st][0], krh, ar);
        ar = mfma16(qh[st][1], kih, ar);
        ar = mfma16(qh[st][1], kil, ar);
        ar = mfma16(ql2[st][1], kih, ar);
        ai = mfma16(qh[st][1], krh, ai);
        ai = mfma16(qh[st][1], krl, ai);
        ai = mfma16(ql2[st][1], krh, ai);
        ai = mfma16(nqh[st], kih, ai);
        ai = mfma16(nqh[st], kil, ai);
        ai = mfma16(nql[st], kih, ai);
        accr[st][mt] = ar; acci[st][mt] = ai;
      }
    }
    __syncthreads();
  }

#pragma unroll
  for (int st = 0; st < 2; ++st)
#pragma unroll
    for (int mt = 0; mt < 4; ++mt)
#pragma unroll
      for (int r = 0; r < 4; ++r) {
        int n = n0 + w * 32 + st * 16 + q4 * 4 + r;
        int m = m0 + mt * 16 + ln;
        int idx = (b << 16) + (n << 8) + m;
        atomicAdd(&SR[idx], accr[st][mt][r]);
        atomicAdd(&SI[idx], acci[st][mt][r]);
      }
}

// ---------------- softmax over n (axis=1), per (b,m) column -----------------
__global__ __launch_bounds__(256) void softmax_kernel(
    const float* __restrict__ sr, const float* __restrict__ si,
    float* __restrict__ am)
{
  const int m = blockIdx.x & 255;
  const int b = blockIdx.x >> 8;
  const int n = threadIdx.x;
  const int idx = (b << 16) + (n << 8) + m;
  float vr = sr[idx], vi = si[idx];
  float mag = sqrtf(vr * vr + vi * vi);
  __shared__ float wmax[4];
  __shared__ float wsum[4];
  float mx = mag;
  #pragma unroll
  for (int off = 1; off < 64; off <<= 1)
    mx = fmaxf(mx, __shfl_xor(mx, off, 64));
  if ((threadIdx.x & 63) == 0) wmax[threadIdx.x >> 6] = mx;
  __syncthreads();
  mx = fmaxf(fmaxf(wmax[0], wmax[1]), fmaxf(wmax[2], wmax[3]));
  float e = expf(mag - mx);
  float sm = e;
  #pragma unroll
  for (int off = 1; off < 64; off <<= 1)
    sm += __shfl_xor(sm, off, 64);
  if ((threadIdx.x & 63) == 0) wsum[threadIdx.x >> 6] = sm;
  __syncthreads();
  float tot = wsum[0] + wsum[1] + wsum[2] + wsum[3];
  am[idx] = e / tot;
}

// ==== freq V: post-BN f32 [c][f][t] -> packed rows (c,t) over f (transpose) =
__global__ __launch_bounds__(256) void vt_transpose(
    const float* __restrict__ y2, __bf16* __restrict__ vh,
    __bf16* __restrict__ vl)
{
  __shared__ float sT[64 * 65];
  const int tid = threadIdx.x;
  const int bpc = blockIdx.y;           // bp*64 + c
  const int bp = bpc >> 6, c = bpc & 63;
  const int f0 = (blockIdx.x >> 2) << 6, t0 = (blockIdx.x & 3) << 6;
  const float* src = y2 + (size_t)bp * PLANE + (size_t)c * SS;
#pragma unroll
  for (int r = 0; r < 4; ++r) {
    int fl = (tid >> 4) + (r << 4);
    int tl = (tid & 15) << 2;
    float4 v = *(const float4*)&src[(f0 + fl) * 256 + t0 + tl];
    sT[fl * 65 + tl + 0] = v.x;
    sT[fl * 65 + tl + 1] = v.y;
    sT[fl * 65 + tl + 2] = v.z;
    sT[fl * 65 + tl + 3] = v.w;
  }
  __syncthreads();
  __bf16* dsth = vh + (((size_t)bp * 16384 + c * 256) << 8);
  __bf16* dstl = vl + (((size_t)bp * 16384 + c * 256) << 8);
#pragma unroll
  for (int r = 0; r < 4; ++r) {
    int tl = (tid >> 4) + (r << 4);
    int fl = (tid & 15) << 2;
    bf16x4v h, l;
#pragma unroll
    for (int e = 0; e < 4; ++e) {
      float vv = sT[(fl + e) * 65 + tl];
      __bf16 hh = (__bf16)vv;
      h[e] = hh; l[e] = (__bf16)(vv - (float)hh);
    }
    *(bf16x4v*)&dsth[(size_t)(t0 + tl) * 256 + f0 + fl] = h;
    *(bf16x4v*)&dstl[(size_t)(t0 + tl) * 256 + f0 + fl] = l;
  }
}

// ======== out[d,n] = sum_m A[n,m] * V[d,m] via split-bf16 MFMA ==============
__global__ __launch_bounds__(256) void av_mfma(
    const float* __restrict__ am, const __bf16* __restrict__ vth,
    const __bf16* __restrict__ vtl, float* __restrict__ out, int freq)
{
  __shared__ __align__(16) char smem[55296];
  __bf16* sVh = (__bf16*)smem;                  // [128][72]
  __bf16* sVl = (__bf16*)(smem + 18432);
  __bf16* sAh = (__bf16*)(smem + 36864);        // [64][72]
  __bf16* sAl = (__bf16*)(smem + 46080);
  const int tid = threadIdx.x;
  const int d0 = blockIdx.x << 7;
  const int n0 = blockIdx.y << 6;
  const int bp = blockIdx.z, b = bp >> 1;
  const int w = tid >> 6, q = (tid >> 4) & 3, ln = tid & 15;
  const __bf16* vhp = vth + (((size_t)bp * 16384 + d0) << 8);
  const __bf16* vlp = vtl + (((size_t)bp * 16384 + d0) << 8);
  float* op = out + (size_t)bp * PLANE;

  f32x4 zero = {0.f, 0.f, 0.f, 0.f};
  f32x4 acc[2][4];
#pragma unroll
  for (int mt = 0; mt < 2; ++mt)
#pragma unroll
    for (int nt = 0; nt < 4; ++nt) acc[mt][nt] = zero;

  for (int m0 = 0; m0 < 256; m0 += 64) {
#pragma unroll
    for (int r = 0; r < 4; ++r) {
      int u = tid + (r << 8);
      int dl = u >> 3, g = (u & 7) << 3;
      *(bf16x8*)&sVh[dl * 72 + g] = *(const bf16x8*)&vhp[dl * 256 + m0 + g];
      *(bf16x8*)&sVl[dl * 72 + g] = *(const bf16x8*)&vlp[dl * 256 + m0 + g];
    }
#pragma unroll
    for (int r = 0; r < 4; ++r) {
      int u = tid + (r << 8);
      int mj = (u & 15) << 2, nl = u >> 4;
      float4 v4 = *(const float4*)&am[(b << 16) + ((n0 + nl) << 8) + m0 + mj];
      float vv[4] = {v4.x, v4.y, v4.z, v4.w};
      bf16x4v h, l;
#pragma unroll
      for (int e = 0; e < 4; ++e) {
        __bf16 hh = (__bf16)vv[e];
        h[e] = hh; l[e] = (__bf16)(vv[e] - (float)hh);
      }
      *(bf16x4v*)&sAh[nl * 72 + mj] = h;
      *(bf16x4v*)&sAl[nl * 72 + mj] = l;
    }
    __syncthreads();

#pragma unroll
    for (int ks = 0; ks < 2; ++ks) {
      bf16x8 vhf[2], vlf[2], ahf[4], alf[4];
#pragma unroll
      for (int mt = 0; mt < 2; ++mt) {
        int off = (w * 32 + mt * 16 + ln) * 72 + ks * 32 + q * 8;
        vhf[mt] = *(const bf16x8*)&sVh[off];
        vlf[mt] = *(const bf16x8*)&sVl[off];
      }
#pragma unroll
      for (int nt = 0; nt < 4; ++nt) {
        int off = (nt * 16 + ln) * 72 + ks * 32 + q * 8;
        ahf[nt] = *(const bf16x8*)&sAh[off];
        alf[nt] = *(const bf16x8*)&sAl[off];
      }
#pragma unroll
      for (int mt = 0; mt < 2; ++mt)
#pragma unroll
        for (int nt = 0; nt < 4; ++nt) {
          f32x4 a = acc[mt][nt];
          a = mfma16(vhf[mt], ahf[nt], a);
          a = mfma16(vhf[mt], alf[nt], a);
          a = mfma16(vlf[mt], ahf[nt], a);
          acc[mt][nt] = a;
        }
    }
    __syncthreads();
  }

  if (!freq) {
#pragma unroll
    for (int mt = 0; mt < 2; ++mt)
#pragma unroll
      for (int nt = 0; nt < 4; ++nt)
#pragma unroll
        for (int r = 0; r < 4; ++r) {
          int row = d0 + w * 32 + mt * 16 + q * 4 + r;
          op[(size_t)row * 256 + n0 + nt * 16 + ln] = acc[mt][nt][r];
        }
  } else {
    float* sO = (float*)smem;   // [128][65]
#pragma unroll
    for (int mt = 0; mt < 2; ++mt)
#pragma unroll
      for (int nt = 0; nt < 4; ++nt)
#pragma unroll
        for (int r = 0; r < 4; ++r)
          sO[(w * 32 + mt * 16 + q * 4 + r) * 65 + nt * 16 + ln] = acc[mt][nt][r];
    __syncthreads();
    const int c = d0 >> 8, t0 = d0 & 255;
    const int dl = (tid & 31) << 2, nb = tid >> 5;
#pragma unroll
    for (int r = 0; r < 8; ++r) {
      int n = nb + (r << 3);
      float4 wv = make_float4(sO[(dl + 0) * 65 + n], sO[(dl + 1) * 65 + n],
                              sO[(dl + 2) * 65 + n], sO[(dl + 3) * 65 + n]);
      size_t addr = (size_t)c * SS + (size_t)(n0 + n) * 256 + t0 + dl;
      float4 o = *(float4*)&op[addr];
      wv.x += o.x; wv.y += o.y; wv.z += o.z; wv.w += o.w;
      *(float4*)&op[addr] = wv;
    }
  }
}

extern "C" void kernel_launch(void* const* d_in, const int* in_sizes, int n_in,
                              void* d_out, int out_size, void* d_ws, size_t ws_size,
                              hipStream_t stream) {
  const float* P    = (const float*)d_in[0];
  const float* Q    = (const float*)d_in[1];
  const float* W    = (const float*)d_in[2];
  const float* g    = (const float*)d_in[4];
  const float* beta = (const float*)d_in[5];
  float* out = (float*)d_out;
  float* ws  = (float*)d_ws;

  float* Y0    = ws;                      // QG (bf16 grouped)
  float* Y1    = Y0 + TEN_ELEMS;          // KG (bf16 grouped)
  float* Y2    = Y1 + TEN_ELEMS;          // V slot; CPART alias during stats
  float* SR    = Y2 + TEN_ELEMS;
  float* SI    = SR + 131072;
  float* AM    = SI + 131072;
  float* MBUCK = AM + 131072;             // 64*2*128 = 16384
  float* CSUM  = MBUCK + 16384;           // 2*16384 = 32768
  float* MSUM  = CSUM + 32768;            // 256
  float* SCALE6 = MSUM + 256;             // 768
  float* SHIFT6 = SCALE6 + 768;           // 768

  // ---- once: input covariance -> BN scale/shift for all 6 roles ----
  hipMemsetAsync(MBUCK, 0, 16384 * sizeof(float), stream);
  stats_cov<<<dim3(256, 2), 256, 0, stream>>>(Q, P, Y2, MBUCK);
  cov_reduce<<<128, 256, 0, stream>>>(Y2, MBUCK, CSUM, MSUM);
  bn_precompute<<<768, 128, 0, stream>>>(CSUM, CSUM + 16384, MSUM, MSUM + 128,
                                         W, g, beta, SCALE6, SHIFT6);

  for (int phase = 0; phase < 2; ++phase) {
    int j0 = phase * 3;
    int freq = phase;
    // Q -> grouped-packed
    cconv_mfma<<<dim3(1024, 2), 256, 0, stream>>>(
        Q, W + (size_t)j0 * 8192, SCALE6 + j0 * 128, SHIFT6 + j0 * 128,
        Y0, freq);
    // K + V fused (stage P once)
    cconv_kv<<<dim3(1024, 2), 256, 0, stream>>>(
        P, W + (size_t)(j0 + 1) * 8192, W + (size_t)(j0 + 2) * 8192,
        SCALE6 + (j0 + 1) * 128, SHIFT6 + (j0 + 1) * 128,
        SCALE6 + (j0 + 2) * 128, SHIFT6 + (j0 + 2) * 128,
        Y1, Y2, freq ? nullptr : (void*)((char*)Y2 + (size_t)TEN_ELEMS * 2),
        freq);

    hipMemsetAsync(SR, 0, 2 * 131072 * sizeof(float), stream);
    score_mfma<<<dim3(8, 32, 2), 256, 0, stream>>>(
        (const __bf16*)Y0, (const __bf16*)Y1, SR, SI);
    softmax_kernel<<<512, 256, 0, stream>>>(SR, SI, AM);

    const __bf16* VTh;
    const __bf16* VTl;
    if (!freq) {
      VTh = (const __bf16*)Y2;
      VTl = (const __bf16*)((char*)Y2 + (size_t)TEN_ELEMS * 2);
    } else {
      vt_transpose<<<dim3(16, 256), 256, 0, stream>>>(
          Y2, (__bf16*)Y0, (__bf16*)((char*)Y0 + (size_t)TEN_ELEMS * 2));
      VTh = (const __bf16*)Y0;
      VTl = (const __bf16*)((char*)Y0 + (size_t)TEN_ELEMS * 2);
    }
    av_mfma<<<dim3(128, 4, 4), 256, 0, stream>>>(AM, VTh, VTl, out, freq);
  }
}

// Round 10
// 708.488 us; speedup vs baseline: 1.0482x; 1.0482x over previous
//
#include <hip/hip_runtime.h>
#include <math.h>

#define SS 65536               // F*T
#define PLANE 4194304          // CC*SS floats per (b,part)
#define TEN_ELEMS 16777216     // 2*2*CC*SS floats per tensor
#define NSAMP 131072.0f        // B*F*T samples per BN channel

typedef __bf16 bf16x8 __attribute__((ext_vector_type(8)));
typedef __bf16 bf16x4v __attribute__((ext_vector_type(4)));
typedef float  f32x4  __attribute__((ext_vector_type(4)));

__device__ inline f32x4 mfma16(bf16x8 a, bf16x8 b, f32x4 c) {
  return __builtin_amdgcn_mfma_f32_16x16x32_bf16(a, b, c, 0, 0, 0);
}
__device__ inline bf16x8 neg8(bf16x8 v) {
  union { bf16x8 b; unsigned u[4]; } t; t.b = v;
#pragma unroll
  for (int i = 0; i < 4; ++i) t.u[i] ^= 0x80008000u;
  return t.b;
}
__device__ inline float bnlrelu(float v, float sc, float sh) {
  float t = fmaf(v, sc, sh);
  return t > 0.f ? t : 0.01f * t;
}

// swizzled element offset of 16B-granule g within row r (rows of 40 elems)
__device__ inline int swz(int r, int g) {
  return r * 40 + (((g ^ (r >> 2) ^ (r >> 4)) & 3) << 3);
}

// ======== input covariance + mean partials: Cwin = Xwin Xwin^T ==============
__global__ __launch_bounds__(256) void stats_cov(
    const float* __restrict__ xQ, const float* __restrict__ xP,
    float* __restrict__ cpart, float* __restrict__ mbuck)
{
  __shared__ __align__(16) __bf16 sXh[128 * 72];
  __shared__ __align__(16) __bf16 sXl[128 * 72];
  const int tid = threadIdx.x;
  const int win = blockIdx.x;             // 0..255 (256-s windows)
  const int tz = blockIdx.y;              // 0=Q, 1=P
  const float* x = tz ? xP : xQ;
  const int w = tid >> 6, q = (tid >> 4) & 3, ln = tid & 15;
  const int pcb = tid >> 4;               // row group owner (16 s-lanes each)
  const int s4 = (tid & 15) * 4;

  f32x4 zero = {0.f, 0.f, 0.f, 0.f};
  f32x4 acc[2][8];
#pragma unroll
  for (int mt = 0; mt < 2; ++mt)
#pragma unroll
    for (int nt = 0; nt < 8; ++nt) acc[mt][nt] = zero;
  float msum[8] = {0.f, 0.f, 0.f, 0.f, 0.f, 0.f, 0.f, 0.f};

  for (int half = 0; half < 8; ++half) {
    const int bb = half >> 2;
    const int sbase = win * 256 + (half & 3) * 64;
#pragma unroll
    for (int r = 0; r < 8; ++r) {
      int pc = pcb + r * 16;
      float4 v4 = *(const float4*)&x[(size_t)(bb * 128 + pc) * SS + sbase + s4];
      msum[r] += v4.x + v4.y + v4.z + v4.w;
      float vv[4] = {v4.x, v4.y, v4.z, v4.w};
      bf16x4v hv, lv;
#pragma unroll
      for (int e = 0; e < 4; ++e) {
        __bf16 h = (__bf16)vv[e];
        hv[e] = h; lv[e] = (__bf16)(vv[e] - (float)h);
      }
      *(bf16x4v*)&sXh[pc * 72 + s4] = hv;
      *(bf16x4v*)&sXl[pc * 72 + s4] = lv;
    }
    __syncthreads();
#pragma unroll
    for (int ks = 0; ks < 2; ++ks) {
      bf16x8 ah[2], al[2];
#pragma unroll
      for (int mt = 0; mt < 2; ++mt) {
        int ra = w * 32 + mt * 16 + ln;
        ah[mt] = *(const bf16x8*)&sXh[ra * 72 + ks * 32 + q * 8];
        al[mt] = *(const bf16x8*)&sXl[ra * 72 + ks * 32 + q * 8];
      }
#pragma unroll
      for (int nt = 0; nt < 8; ++nt) {
        int rb = nt * 16 + ln;
        bf16x8 bh = *(const bf16x8*)&sXh[rb * 72 + ks * 32 + q * 8];
        bf16x8 bl = *(const bf16x8*)&sXl[rb * 72 + ks * 32 + q * 8];
#pragma unroll
        for (int mt = 0; mt < 2; ++mt) {
          f32x4 a = acc[mt][nt];
          a = mfma16(ah[mt], bh, a);
          a = mfma16(ah[mt], bl, a);
          a = mfma16(al[mt], bh, a);
          acc[mt][nt] = a;
        }
      }
    }
    __syncthreads();
  }
#pragma unroll
  for (int r = 0; r < 8; ++r) {
    float v = msum[r];
#pragma unroll
    for (int off = 1; off < 16; off <<= 1) v += __shfl_xor(v, off, 64);
    if (ln == 0)
      atomicAdd(&mbuck[((win & 63) * 2 + tz) * 128 + pcb + r * 16], v);
  }
  float* cp = cpart + ((size_t)tz * 256 + win) * 16384;
#pragma unroll
  for (int mt = 0; mt < 2; ++mt)
#pragma unroll
    for (int nt = 0; nt < 8; ++nt)
#pragma unroll
      for (int r = 0; r < 4; ++r) {
        int row = w * 32 + mt * 16 + q * 4 + r;
        int col = nt * 16 + ln;
        cp[row * 128 + col] = acc[mt][nt][r];
      }
}

// ======== reduce window partials ============================================
__global__ __launch_bounds__(256) void cov_reduce(
    const float* __restrict__ cpart, const float* __restrict__ mbuck,
    float* __restrict__ csum, float* __restrict__ msum)
{
  int i = blockIdx.x * 256 + threadIdx.x;   // 0..32767
  int tz = i >> 14, e = i & 16383;
  const float* p = cpart + (size_t)tz * 256 * 16384 + e;
  float s = 0.f;
#pragma unroll 4
  for (int k = 0; k < 256; ++k) s += p[(size_t)k * 16384];
  csum[i] = s;
  if (i < 256) {
    int t2 = i >> 7, row = i & 127;
    float sm2 = 0.f;
#pragma unroll 4
    for (int k = 0; k < 64; ++k) sm2 += mbuck[(k * 2 + t2) * 128 + row];
    msum[i] = sm2;
  }
}

// ======== BN scale/shift from covariance ====================================
__global__ void bn_precompute(
    const float* __restrict__ Cq, const float* __restrict__ Cp,
    const float* __restrict__ mq, const float* __restrict__ mp,
    const float* __restrict__ W, const float* __restrict__ g,
    const float* __restrict__ beta,
    float* __restrict__ scale6, float* __restrict__ shift6)
{
  const int rr = blockIdx.x >> 7;       // role 0..5
  const int o  = blockIdx.x & 127;      // output pc
  const int i  = threadIdx.x;           // input pc 0..127
  const float* C = (rr % 3 == 0) ? Cq : Cp;
  const float* m = (rr % 3 == 0) ? mq : mp;
  const int po = o >> 6, co = o & 63;
  const int pi = i >> 6, ci = i & 63;
  float wv = W[rr * 8192 + ((po ^ pi) << 12) + co * 64 + ci];
  if (po == 0 && pi == 1) wv = -wv;
  __shared__ float sW[128];
  sW[i] = wv;
  __syncthreads();
  float t = 0.f;
  const float* crow = C + i * 128;
#pragma unroll 8
  for (int j = 0; j < 128; ++j) t += crow[j] * sW[j];
  float pv = wv * t;
  float pm = wv * m[i];
#pragma unroll
  for (int off = 1; off < 64; off <<= 1) {
    pv += __shfl_xor(pv, off, 64);
    pm += __shfl_xor(pm, off, 64);
  }
  __shared__ float red[4];
  if ((i & 63) == 0) { red[(i >> 6) * 2] = pv; red[(i >> 6) * 2 + 1] = pm; }
  __syncthreads();
  if (i == 0) {
    float v = red[0] + red[2];
    float wm = red[1] + red[3];
    float muT = wm / NSAMP;
    float var = v / NSAMP - muT * muT;
    float sc = g[rr * 128 + o] * rsqrtf(var + 1e-5f);
    scale6[rr * 128 + o] = sc;
    shift6[rr * 128 + o] = beta[rr * 128 + o] - muT * sc;
  }
}

// ============ Q conv: 1x1 complex conv + BN/leaky -> grouped-packed =========
__global__ __launch_bounds__(256) void cconv_mfma(
    const float* __restrict__ x, const float* __restrict__ Wj,
    const float* __restrict__ scale, const float* __restrict__ shiftp,
    void* __restrict__ outA, int freq)
{
  __shared__ __align__(16) char smemBlk[34816];
  __bf16* sBh = (__bf16*)smemBlk;               // [64 s][136 pc]
  __bf16* sBl = (__bf16*)(smemBlk + 17408);
  const int tid = threadIdx.x;
  const int b = blockIdx.y;
  const int s0 = blockIdx.x << 6;
  const int w = tid >> 6, q = (tid >> 4) & 3, ln = tid & 15;

  bf16x8 ah[2][4], al[2][4];
#pragma unroll
  for (int mt = 0; mt < 2; ++mt) {
    int row = w * 32 + mt * 16 + ln;
    int po = row >> 6, co = row & 63;
#pragma unroll
    for (int ks = 0; ks < 4; ++ks) {
      bf16x8 vh, vl;
#pragma unroll
      for (int j = 0; j < 8; ++j) {
        int k = ks * 32 + q * 8 + j;
        int pi = k >> 6, c = k & 63;
        float v = Wj[((po ^ pi) << 12) + co * 64 + c];
        if (po == 0 && pi == 1) v = -v;
        __bf16 h = (__bf16)v;
        vh[j] = h;
        vl[j] = (__bf16)(v - (float)h);
      }
      ah[mt][ks] = vh; al[mt][ks] = vl;
    }
  }

#pragma unroll
  for (int ph = 0; ph < 2; ++ph) {
    int pc = ph * 64 + (tid & 63);
    const float* rowp = x + (size_t)(b * 128 + pc) * SS + s0;
#pragma unroll
    for (int sh2 = 0; sh2 < 2; ++sh2)
#pragma unroll
      for (int sc2 = 0; sc2 < 2; ++sc2) {
        int sl = ((tid >> 6) << 3) + sh2 * 32 + sc2 * 4;
        float4 rd = *(const float4*)&rowp[sl];
        float vv[4] = {rd.x, rd.y, rd.z, rd.w};
#pragma unroll
        for (int e = 0; e < 4; ++e) {
          __bf16 h = (__bf16)vv[e];
          sBh[(sl + e) * 136 + pc] = h;
          sBl[(sl + e) * 136 + pc] = (__bf16)(vv[e] - (float)h);
        }
      }
  }
  __syncthreads();

  f32x4 zero = {0.f, 0.f, 0.f, 0.f};
  f32x4 acc[2][4];
#pragma unroll
  for (int mt = 0; mt < 2; ++mt)
#pragma unroll
    for (int nt = 0; nt < 4; ++nt) acc[mt][nt] = zero;

#pragma unroll
  for (int ks = 0; ks < 4; ++ks) {
    bf16x8 bh[4], bl[4];
#pragma unroll
    for (int nt = 0; nt < 4; ++nt) {
      int off = (nt * 16 + ln) * 136 + ks * 32 + q * 8;
      bh[nt] = *(const bf16x8*)&sBh[off];
      bl[nt] = *(const bf16x8*)&sBl[off];
    }
#pragma unroll
    for (int mt = 0; mt < 2; ++mt)
#pragma unroll
      for (int nt = 0; nt < 4; ++nt) {
        acc[mt][nt] = mfma16(ah[mt][ks], bh[nt], acc[mt][nt]);
        acc[mt][nt] = mfma16(ah[mt][ks], bl[nt], acc[mt][nt]);
        acc[mt][nt] = mfma16(al[mt][ks], bh[nt], acc[mt][nt]);
      }
  }

  float scv[2][4], shv[2][4];
#pragma unroll
  for (int mt = 0; mt < 2; ++mt)
#pragma unroll
    for (int r = 0; r < 4; ++r) {
      int row = w * 32 + mt * 16 + q * 4 + r;
      scv[mt][r] = scale[row];
      shv[mt][r] = shiftp[row];
    }

  // grouped-packed epilogue (LDS transpose)
  __syncthreads();
  float* sT = (float*)smemBlk;     // [64 t][133]
#pragma unroll
  for (int mt = 0; mt < 2; ++mt)
#pragma unroll
    for (int nt = 0; nt < 4; ++nt)
#pragma unroll
      for (int r = 0; r < 4; ++r)
        sT[(nt * 16 + ln) * 133 + (w * 32 + mt * 16 + q * 4 + r)] =
            bnlrelu(acc[mt][nt][r], scv[mt][r], shv[mt][r]);
  __syncthreads();
  const int pch = tid >> 6, tl = tid & 63;
  float vv[32];
#pragma unroll
  for (int j2 = 0; j2 < 8; ++j2)
    *(f32x4*)&vv[j2 * 4] = *(const f32x4*)&sT[tl * 133 + pch * 32 + j2 * 4];
  bf16x8 hh[4], ll[4];
#pragma unroll
  for (int j2 = 0; j2 < 4; ++j2)
#pragma unroll
    for (int e = 0; e < 8; ++e) {
      float v = vv[j2 * 8 + e];
      __bf16 h = (__bf16)v;
      hh[j2][e] = h; ll[j2][e] = (__bf16)(v - (float)h);
    }
  __bf16* out = (__bf16*)outA;
  if (!freq) {
    const int p = pch >> 1, ch2 = pch & 1;
    int chunk = (s0 >> 8) * 2 + ch2;
    int tok = (s0 & 255) + tl;
    size_t a = (size_t)(b * 2 + p) * (2 * (size_t)PLANE) +
               ((size_t)chunk * 256 + tok) * 64;
#pragma unroll
    for (int j2 = 0; j2 < 4; ++j2) {
      *(bf16x8*)&out[a + j2 * 8]      = hh[j2];
      *(bf16x8*)&out[a + 32 + j2 * 8] = ll[j2];
    }
  } else {
    __syncthreads();
    __bf16* sP = (__bf16*)smemBlk;   // [256 groups][64]
    __bf16* me = sP + tid * 64;
#pragma unroll
    for (int j2 = 0; j2 < 4; ++j2) {
      *(bf16x8*)&me[j2 * 8]      = hh[j2];
      *(bf16x8*)&me[32 + j2 * 8] = ll[j2];
    }
    __syncthreads();
#pragma unroll
    for (int r2 = 0; r2 < 8; ++r2) {
      int u = tid + (r2 << 8);
      int g2 = u >> 3, piece = u & 7;
      int pch2 = g2 >> 6, t2 = g2 & 63;
      int chunk = ((s0 & 255) + t2) * 2 + (pch2 & 1);
      int tok = s0 >> 8;
      size_t a = (size_t)(b * 2 + (pch2 >> 1)) * (2 * (size_t)PLANE) +
                 ((size_t)chunk * 256 + tok) * 64 + piece * 8;
      *(bf16x8*)&out[a] = *(const bf16x8*)&sP[(size_t)u * 8];
    }
  }
}

// ============ fused K+V conv: stage P once, two weight passes ===============
__global__ __launch_bounds__(256) void cconv_kv(
    const float* __restrict__ x,
    const float* __restrict__ Wk, const float* __restrict__ Wv,
    const float* __restrict__ scK, const float* __restrict__ shK,
    const float* __restrict__ scV, const float* __restrict__ shV,
    void* __restrict__ outK, void* __restrict__ outVa,
    void* __restrict__ outVb, int freq)
{
  __shared__ __align__(16) char smemBlk[34816];
  __bf16* sBh = (__bf16*)smemBlk;               // [64 s][136 pc]
  __bf16* sBl = (__bf16*)(smemBlk + 17408);
  const int tid = threadIdx.x;
  const int b = blockIdx.y;
  const int s0 = blockIdx.x << 6;
  const int w = tid >> 6, q = (tid >> 4) & 3, ln = tid & 15;

  // stage input once
#pragma unroll
  for (int ph = 0; ph < 2; ++ph) {
    int pc = ph * 64 + (tid & 63);
    const float* rowp = x + (size_t)(b * 128 + pc) * SS + s0;
#pragma unroll
    for (int sh2 = 0; sh2 < 2; ++sh2)
#pragma unroll
      for (int sc2 = 0; sc2 < 2; ++sc2) {
        int sl = ((tid >> 6) << 3) + sh2 * 32 + sc2 * 4;
        float4 rd = *(const float4*)&rowp[sl];
        float vv[4] = {rd.x, rd.y, rd.z, rd.w};
#pragma unroll
        for (int e = 0; e < 4; ++e) {
          __bf16 h = (__bf16)vv[e];
          sBh[(sl + e) * 136 + pc] = h;
          sBl[(sl + e) * 136 + pc] = (__bf16)(vv[e] - (float)h);
        }
      }
  }
  __syncthreads();

  f32x4 zero = {0.f, 0.f, 0.f, 0.f};
  f32x4 accKV[2][2][4];
#pragma unroll
  for (int role = 0; role < 2; ++role)
#pragma unroll
    for (int mt = 0; mt < 2; ++mt)
#pragma unroll
      for (int nt = 0; nt < 4; ++nt) accKV[role][mt][nt] = zero;

  for (int role = 0; role < 2; ++role) {
    const float* Wj = role ? Wv : Wk;
    bf16x8 ah[2][4], al[2][4];
#pragma unroll
    for (int mt = 0; mt < 2; ++mt) {
      int row = w * 32 + mt * 16 + ln;
      int po = row >> 6, co = row & 63;
#pragma unroll
      for (int ks = 0; ks < 4; ++ks) {
        bf16x8 vh, vl;
#pragma unroll
        for (int j = 0; j < 8; ++j) {
          int k = ks * 32 + q * 8 + j;
          int pi = k >> 6, c = k & 63;
          float v = Wj[((po ^ pi) << 12) + co * 64 + c];
          if (po == 0 && pi == 1) v = -v;
          __bf16 h = (__bf16)v;
          vh[j] = h;
          vl[j] = (__bf16)(v - (float)h);
        }
        ah[mt][ks] = vh; al[mt][ks] = vl;
      }
    }
#pragma unroll
    for (int ks = 0; ks < 4; ++ks) {
      bf16x8 bh[4], bl[4];
#pragma unroll
      for (int nt = 0; nt < 4; ++nt) {
        int off = (nt * 16 + ln) * 136 + ks * 32 + q * 8;
        bh[nt] = *(const bf16x8*)&sBh[off];
        bl[nt] = *(const bf16x8*)&sBl[off];
      }
#pragma unroll
      for (int mt = 0; mt < 2; ++mt)
#pragma unroll
        for (int nt = 0; nt < 4; ++nt) {
          f32x4 a = accKV[role][mt][nt];
          a = mfma16(ah[mt][ks], bh[nt], a);
          a = mfma16(ah[mt][ks], bl[nt], a);
          a = mfma16(al[mt][ks], bh[nt], a);
          accKV[role][mt][nt] = a;
        }
    }
  }

  // BN params
  float scvK[2][4], shvK[2][4], scvV[2][4], shvV[2][4];
#pragma unroll
  for (int mt = 0; mt < 2; ++mt)
#pragma unroll
    for (int r = 0; r < 4; ++r) {
      int row = w * 32 + mt * 16 + q * 4 + r;
      scvK[mt][r] = scK[row]; shvK[mt][r] = shK[row];
      scvV[mt][r] = scV[row]; shvV[mt][r] = shV[row];
    }

  // ---- V epilogue (no LDS) ----
  if (!freq) {
    __bf16* vh = (__bf16*)outVa;
    __bf16* vl = (__bf16*)outVb;
    const int f = s0 >> 8, t0 = s0 & 255;
#pragma unroll
    for (int mt = 0; mt < 2; ++mt)
#pragma unroll
      for (int r = 0; r < 4; ++r) {
        int row = w * 32 + mt * 16 + q * 4 + r;
        int p = row >> 6, c = row & 63;
        size_t rbase = ((size_t)((b * 2 + p) * 16384 + c * 256 + f)) * 256 + t0;
#pragma unroll
        for (int nt = 0; nt < 4; ++nt) {
          float v = bnlrelu(accKV[1][mt][nt][r], scvV[mt][r], shvV[mt][r]);
          __bf16 h = (__bf16)v;
          vh[rbase + nt * 16 + ln] = h;
          vl[rbase + nt * 16 + ln] = (__bf16)(v - (float)h);
        }
      }
  } else {
    float* y = (float*)outVa;
#pragma unroll
    for (int mt = 0; mt < 2; ++mt)
#pragma unroll
      for (int r = 0; r < 4; ++r) {
        int row = w * 32 + mt * 16 + q * 4 + r;
#pragma unroll
        for (int nt = 0; nt < 4; ++nt)
          y[(size_t)(b * 128 + row) * SS + s0 + nt * 16 + ln] =
              bnlrelu(accKV[1][mt][nt][r], scvV[mt][r], shvV[mt][r]);
      }
  }

  // ---- K grouped-packed epilogue (LDS scratch after barrier) ----
  __syncthreads();
  float* sT = (float*)smemBlk;     // [64 t][133]
#pragma unroll
  for (int mt = 0; mt < 2; ++mt)
#pragma unroll
    for (int nt = 0; nt < 4; ++nt)
#pragma unroll
      for (int r = 0; r < 4; ++r)
        sT[(nt * 16 + ln) * 133 + (w * 32 + mt * 16 + q * 4 + r)] =
            bnlrelu(accKV[0][mt][nt][r], scvK[mt][r], shvK[mt][r]);
  __syncthreads();
  const int pch = tid >> 6, tl = tid & 63;
  float vv[32];
#pragma unroll
  for (int j2 = 0; j2 < 8; ++j2)
    *(f32x4*)&vv[j2 * 4] = *(const f32x4*)&sT[tl * 133 + pch * 32 + j2 * 4];
  bf16x8 hh[4], ll[4];
#pragma unroll
  for (int j2 = 0; j2 < 4; ++j2)
#pragma unroll
    for (int e = 0; e < 8; ++e) {
      float v = vv[j2 * 8 + e];
      __bf16 h = (__bf16)v;
      hh[j2][e] = h; ll[j2][e] = (__bf16)(v - (float)h);
    }
  __bf16* out = (__bf16*)outK;
  if (!freq) {
    const int p = pch >> 1, ch2 = pch & 1;
    int chunk = (s0 >> 8) * 2 + ch2;
    int tok = (s0 & 255) + tl;
    size_t a = (size_t)(b * 2 + p) * (2 * (size_t)PLANE) +
               ((size_t)chunk * 256 + tok) * 64;
#pragma unroll
    for (int j2 = 0; j2 < 4; ++j2) {
      *(bf16x8*)&out[a + j2 * 8]      = hh[j2];
      *(bf16x8*)&out[a + 32 + j2 * 8] = ll[j2];
    }
  } else {
    __syncthreads();
    __bf16* sP = (__bf16*)smemBlk;   // [256 groups][64]
    __bf16* me = sP + tid * 64;
#pragma unroll
    for (int j2 = 0; j2 < 4; ++j2) {
      *(bf16x8*)&me[j2 * 8]      = hh[j2];
      *(bf16x8*)&me[32 + j2 * 8] = ll[j2];
    }
    __syncthreads();
#pragma unroll
    for (int r2 = 0; r2 < 8; ++r2) {
      int u = tid + (r2 << 8);
      int g2 = u >> 3, piece = u & 7;
      int pch2 = g2 >> 6, t2 = g2 & 63;
      int chunk = ((s0 & 255) + t2) * 2 + (pch2 & 1);
      int tok = s0 >> 8;
      size_t a = (size_t)(b * 2 + (pch2 >> 1)) * (2 * (size_t)PLANE) +
                 ((size_t)chunk * 256 + tok) * 64 + piece * 8;
      *(bf16x8*)&out[a] = *(const bf16x8*)&sP[(size_t)u * 8];
    }
  }
}

// ============ complex scores (split-bf16 MFMA, split-K, atomics) ============
// Uniform grouped reads (chunk-major [chunk][tok][32hi|32lo]); direct staging.
__global__ __launch_bounds__(256) void score_mfma(
    const __bf16* __restrict__ qt, const __bf16* __restrict__ kt,
    float* __restrict__ SR, float* __restrict__ SI)
{
  __shared__ __align__(16) __bf16 sQh[2 * 128 * 40], sQl[2 * 128 * 40];
  __shared__ __align__(16) __bf16 sKh[2 * 64 * 40],  sKl[2 * 64 * 40];
  const int tid = threadIdx.x;
  const int sid = blockIdx.x + (blockIdx.y << 3) + (blockIdx.z << 8);
  const int kk = sid & 7, tt = sid >> 3;
  const int n0 = (kk & 1) << 7;
  const int b  = (kk >> 1) & 1;
  const int m0 = (tt & 3) << 6;
  const int g0 = (((kk >> 2) << 4) + (tt >> 2)) << 4;   // 32 splits x 16 chunks
  const int w = tid >> 6, q4 = (tid >> 4) & 3, ln = tid & 15;
  const size_t pb = (size_t)(b * 2) * (2 * (size_t)PLANE);

  f32x4 zero = {0.f, 0.f, 0.f, 0.f};
  f32x4 accr[2][4], acci[2][4];
#pragma unroll
  for (int st = 0; st < 2; ++st)
#pragma unroll
    for (int mt = 0; mt < 4; ++mt) { accr[st][mt] = zero; acci[st][mt] = zero; }

  for (int ch = 0; ch < 16; ++ch) {
    const int g = g0 + ch;
    const int Gq = g * 256 + n0;
    const int Gk = g * 256 + m0;
#pragma unroll
    for (int r = 0; r < 4; ++r) {
      int u = tid + (r << 8);
      int g_ = u & 3, tok = (u >> 2) & 127, p = u >> 9;
      size_t a = pb + (size_t)p * (2 * (size_t)PLANE) +
                 (size_t)(Gq + tok) * 64 + (g_ << 3);
      int dst = swz(p * 128 + tok, g_);
      *(bf16x8*)&sQh[dst] = *(const bf16x8*)&qt[a];
      *(bf16x8*)&sQl[dst] = *(const bf16x8*)&qt[a + 32];
    }
#pragma unroll
    for (int r = 0; r < 2; ++r) {
      int u = tid + (r << 8);
      int g_ = u & 3, tok = (u >> 2) & 63, p = u >> 8;
      size_t a = pb + (size_t)p * (2 * (size_t)PLANE) +
                 (size_t)(Gk + tok) * 64 + (g_ << 3);
      int dst = swz(p * 64 + tok, g_);
      *(bf16x8*)&sKh[dst] = *(const bf16x8*)&kt[a];
      *(bf16x8*)&sKl[dst] = *(const bf16x8*)&kt[a + 32];
    }
    __syncthreads();

    bf16x8 qh[2][2], ql2[2][2], nqh[2], nql[2];
#pragma unroll
    for (int st = 0; st < 2; ++st) {
      int tokn = w * 32 + st * 16 + ln;
#pragma unroll
      for (int p = 0; p < 2; ++p) {
        int off = swz(p * 128 + tokn, q4);
        qh[st][p]  = *(const bf16x8*)&sQh[off];
        ql2[st][p] = *(const bf16x8*)&sQl[off];
      }
      nqh[st] = neg8(qh[st][0]);
      nql[st] = neg8(ql2[st][0]);
    }
#pragma unroll
    for (int mt = 0; mt < 4; ++mt) {
      int tk = mt * 16 + ln;
      int offr = swz(tk, q4), offi = swz(64 + tk, q4);
      bf16x8 krh = *(const bf16x8*)&sKh[offr];
      bf16x8 krl = *(const bf16x8*)&sKl[offr];
      bf16x8 kih = *(const bf16x8*)&sKh[offi];
      bf16x8 kil = *(const bf16x8*)&sKl[offi];
#pragma unroll
      for (int st = 0; st < 2; ++st) {
        f32x4 ar = accr[st][mt], ai = acci[st][mt];
        ar = mfma16(qh[st][0], krh, ar);
        ar = mfma16(qh[st][0], krl, ar);
        ar = mfma16(ql2[st][0], krh, ar);
        ar = mfma16(qh[st][1], kih, ar);
        ar = mfma16(qh[st][1], kil, ar);
        ar = mfma16(ql2[st][1], kih, ar);
        ai = mfma16(qh[st][1], krh, ai);
        ai = mfma16(qh[st][1], krl, ai);
        ai = mfma16(ql2[st][1], krh, ai);
        ai = mfma16(nqh[st], kih, ai);
        ai = mfma16(nqh[st], kil, ai);
        ai = mfma16(nql[st], kih, ai);
        accr[st][mt] = ar; acci[st][mt] = ai;
      }
    }
    __syncthreads();
  }

#pragma unroll
  for (int st = 0; st < 2; ++st)
#pragma unroll
    for (int mt = 0; mt < 4; ++mt)
#pragma unroll
      for (int r = 0; r < 4; ++r) {
        int n = n0 + w * 32 + st * 16 + q4 * 4 + r;
        int m = m0 + mt * 16 + ln;
        int idx = (b << 16) + (n << 8) + m;
        atomicAdd(&SR[idx], accr[st][mt][r]);
        atomicAdd(&SI[idx], acci[st][mt][r]);
      }
}

// ---------------- softmax over n (axis=1), per (b,m) column -----------------
__global__ __launch_bounds__(256) void softmax_kernel(
    const float* __restrict__ sr, const float* __restrict__ si,
    float* __restrict__ am)
{
  const int m = blockIdx.x & 255;
  const int b = blockIdx.x >> 8;
  const int n = threadIdx.x;
  const int idx = (b << 16) + (n << 8) + m;
  float vr = sr[idx], vi = si[idx];
  float mag = sqrtf(vr * vr + vi * vi);
  __shared__ float wmax[4];
  __shared__ float wsum[4];
  float mx = mag;
  #pragma unroll
  for (int off = 1; off < 64; off <<= 1)
    mx = fmaxf(mx, __shfl_xor(mx, off, 64));
  if ((threadIdx.x & 63) == 0) wmax[threadIdx.x >> 6] = mx;
  __syncthreads();
  mx = fmaxf(fmaxf(wmax[0], wmax[1]), fmaxf(wmax[2], wmax[3]));
  float e = expf(mag - mx);
  float sm = e;
  #pragma unroll
  for (int off = 1; off < 64; off <<= 1)
    sm += __shfl_xor(sm, off, 64);
  if ((threadIdx.x & 63) == 0) wsum[threadIdx.x >> 6] = sm;
  __syncthreads();
  float tot = wsum[0] + wsum[1] + wsum[2] + wsum[3];
  am[idx] = e / tot;
}

// ==== freq V: post-BN f32 [c][f][t] -> packed rows (c,t) over f (transpose) =
__global__ __launch_bounds__(256) void vt_transpose(
    const float* __restrict__ y2, __bf16* __restrict__ vh,
    __bf16* __restrict__ vl)
{
  __shared__ float sT[64 * 65];
  const int tid = threadIdx.x;
  const int bpc = blockIdx.y;           // bp*64 + c
  const int bp = bpc >> 6, c = bpc & 63;
  const int f0 = (blockIdx.x >> 2) << 6, t0 = (blockIdx.x & 3) << 6;
  const float* src = y2 + (size_t)bp * PLANE + (size_t)c * SS;
#pragma unroll
  for (int r = 0; r < 4; ++r) {
    int fl = (tid >> 4) + (r << 4);
    int tl = (tid & 15) << 2;
    float4 v = *(const float4*)&src[(f0 + fl) * 256 + t0 + tl];
    sT[fl * 65 + tl + 0] = v.x;
    sT[fl * 65 + tl + 1] = v.y;
    sT[fl * 65 + tl + 2] = v.z;
    sT[fl * 65 + tl + 3] = v.w;
  }
  __syncthreads();
  __bf16* dsth = vh + (((size_t)bp * 16384 + c * 256) << 8);
  __bf16* dstl = vl + (((size_t)bp * 16384 + c * 256) << 8);
#pragma unroll
  for (int r = 0; r < 4; ++r) {
    int tl = (tid >> 4) + (r << 4);
    int fl = (tid & 15) << 2;
    bf16x4v h, l;
#pragma unroll
    for (int e = 0; e < 4; ++e) {
      float vv = sT[(fl + e) * 65 + tl];
      __bf16 hh = (__bf16)vv;
      h[e] = hh; l[e] = (__bf16)(vv - (float)hh);
    }
    *(bf16x4v*)&dsth[(size_t)(t0 + tl) * 256 + f0 + fl] = h;
    *(bf16x4v*)&dstl[(size_t)(t0 + tl) * 256 + f0 + fl] = l;
  }
}

// ======== out[d,n] = sum_m A[n,m] * V[d,m] via split-bf16 MFMA ==============
__global__ __launch_bounds__(256) void av_mfma(
    const float* __restrict__ am, const __bf16* __restrict__ vth,
    const __bf16* __restrict__ vtl, float* __restrict__ out, int freq)
{
  __shared__ __align__(16) char smem[55296];
  __bf16* sVh = (__bf16*)smem;                  // [128][72]
  __bf16* sVl = (__bf16*)(smem + 18432);
  __bf16* sAh = (__bf16*)(smem + 36864);        // [64][72]
  __bf16* sAl = (__bf16*)(smem + 46080);
  const int tid = threadIdx.x;
  const int d0 = blockIdx.x << 7;
  const int n0 = blockIdx.y << 6;
  const int bp = blockIdx.z, b = bp >> 1;
  const int w = tid >> 6, q = (tid >> 4) & 3, ln = tid & 15;
  const __bf16* vhp = vth + (((size_t)bp * 16384 + d0) << 8);
  const __bf16* vlp = vtl + (((size_t)bp * 16384 + d0) << 8);
  float* op = out + (size_t)bp * PLANE;

  f32x4 zero = {0.f, 0.f, 0.f, 0.f};
  f32x4 acc[2][4];
#pragma unroll
  for (int mt = 0; mt < 2; ++mt)
#pragma unroll
    for (int nt = 0; nt < 4; ++nt) acc[mt][nt] = zero;

  for (int m0 = 0; m0 < 256; m0 += 64) {
#pragma unroll
    for (int r = 0; r < 4; ++r) {
      int u = tid + (r << 8);
      int dl = u >> 3, g = (u & 7) << 3;
      *(bf16x8*)&sVh[dl * 72 + g] = *(const bf16x8*)&vhp[dl * 256 + m0 + g];
      *(bf16x8*)&sVl[dl * 72 + g] = *(const bf16x8*)&vlp[dl * 256 + m0 + g];
    }
#pragma unroll
    for (int r = 0; r < 4; ++r) {
      int u = tid + (r << 8);
      int mj = (u & 15) << 2, nl = u >> 4;
      float4 v4 = *(const float4*)&am[(b << 16) + ((n0 + nl) << 8) + m0 + mj];
      float vv[4] = {v4.x, v4.y, v4.z, v4.w};
      bf16x4v h, l;
#pragma unroll
      for (int e = 0; e < 4; ++e) {
        __bf16 hh = (__bf16)vv[e];
        h[e] = hh; l[e] = (__bf16)(vv[e] - (float)hh);
      }
      *(bf16x4v*)&sAh[nl * 72 + mj] = h;
      *(bf16x4v*)&sAl[nl * 72 + mj] = l;
    }
    __syncthreads();

#pragma unroll
    for (int ks = 0; ks < 2; ++ks) {
      bf16x8 vhf[2], vlf[2], ahf[4], alf[4];
#pragma unroll
      for (int mt = 0; mt < 2; ++mt) {
        int off = (w * 32 + mt * 16 + ln) * 72 + ks * 32 + q * 8;
        vhf[mt] = *(const bf16x8*)&sVh[off];
        vlf[mt] = *(const bf16x8*)&sVl[off];
      }
#pragma unroll
      for (int nt = 0; nt < 4; ++nt) {
        int off = (nt * 16 + ln) * 72 + ks * 32 + q * 8;
        ahf[nt] = *(const bf16x8*)&sAh[off];
        alf[nt] = *(const bf16x8*)&sAl[off];
      }
#pragma unroll
      for (int mt = 0; mt < 2; ++mt)
#pragma unroll
        for (int nt = 0; nt < 4; ++nt) {
          f32x4 a = acc[mt][nt];
          a = mfma16(vhf[mt], ahf[nt], a);
          a = mfma16(vhf[mt], alf[nt], a);
          a = mfma16(vlf[mt], ahf[nt], a);
          acc[mt][nt] = a;
        }
    }
    __syncthreads();
  }

  if (!freq) {
#pragma unroll
    for (int mt = 0; mt < 2; ++mt)
#pragma unroll
      for (int nt = 0; nt < 4; ++nt)
#pragma unroll
        for (int r = 0; r < 4; ++r) {
          int row = d0 + w * 32 + mt * 16 + q * 4 + r;
          op[(size_t)row * 256 + n0 + nt * 16 + ln] = acc[mt][nt][r];
        }
  } else {
    float* sO = (float*)smem;   // [128][65]
#pragma unroll
    for (int mt = 0; mt < 2; ++mt)
#pragma unroll
      for (int nt = 0; nt < 4; ++nt)
#pragma unroll
        for (int r = 0; r < 4; ++r)
          sO[(w * 32 + mt * 16 + q * 4 + r) * 65 + nt * 16 + ln] = acc[mt][nt][r];
    __syncthreads();
    const int c = d0 >> 8, t0 = d0 & 255;
    const int dl = (tid & 31) << 2, nb = tid >> 5;
#pragma unroll
    for (int r = 0; r < 8; ++r) {
      int n = nb + (r << 3);
      float4 wv = make_float4(sO[(dl + 0) * 65 + n], sO[(dl + 1) * 65 + n],
                              sO[(dl + 2) * 65 + n], sO[(dl + 3) * 65 + n]);
      size_t addr = (size_t)c * SS + (size_t)(n0 + n) * 256 + t0 + dl;
      float4 o = *(float4*)&op[addr];
      wv.x += o.x; wv.y += o.y; wv.z += o.z; wv.w += o.w;
      *(float4*)&op[addr] = wv;
    }
  }
}

extern "C" void kernel_launch(void* const* d_in, const int* in_sizes, int n_in,
                              void* d_out, int out_size, void* d_ws, size_t ws_size,
                              hipStream_t stream) {
  const float* P    = (const float*)d_in[0];
  const float* Q    = (const float*)d_in[1];
  const float* W    = (const float*)d_in[2];
  const float* g    = (const float*)d_in[4];
  const float* beta = (const float*)d_in[5];
  float* out = (float*)d_out;
  float* ws  = (float*)d_ws;

  float* Y0    = ws;                      // QG (bf16 grouped)
  float* Y1    = Y0 + TEN_ELEMS;          // KG (bf16 grouped)
  float* Y2    = Y1 + TEN_ELEMS;          // V slot; CPART alias during stats
  float* SR    = Y2 + TEN_ELEMS;
  float* SI    = SR + 131072;
  float* AM    = SI + 131072;
  float* MBUCK = AM + 131072;             // 64*2*128 = 16384
  float* CSUM  = MBUCK + 16384;           // 2*16384 = 32768
  float* MSUM  = CSUM + 32768;            // 256
  float* SCALE6 = MSUM + 256;             // 768
  float* SHIFT6 = SCALE6 + 768;           // 768

  // ---- once: input covariance -> BN scale/shift for all 6 roles ----
  hipMemsetAsync(MBUCK, 0, 16384 * sizeof(float), stream);
  stats_cov<<<dim3(256, 2), 256, 0, stream>>>(Q, P, Y2, MBUCK);
  cov_reduce<<<128, 256, 0, stream>>>(Y2, MBUCK, CSUM, MSUM);
  bn_precompute<<<768, 128, 0, stream>>>(CSUM, CSUM + 16384, MSUM, MSUM + 128,
                                         W, g, beta, SCALE6, SHIFT6);

  for (int phase = 0; phase < 2; ++phase) {
    int j0 = phase * 3;
    int freq = phase;
    // Q -> grouped-packed
    cconv_mfma<<<dim3(1024, 2), 256, 0, stream>>>(
        Q, W + (size_t)j0 * 8192, SCALE6 + j0 * 128, SHIFT6 + j0 * 128,
        Y0, freq);
    // K + V fused (stage P once)
    cconv_kv<<<dim3(1024, 2), 256, 0, stream>>>(
        P, W + (size_t)(j0 + 1) * 8192, W + (size_t)(j0 + 2) * 8192,
        SCALE6 + (j0 + 1) * 128, SHIFT6 + (j0 + 1) * 128,
        SCALE6 + (j0 + 2) * 128, SHIFT6 + (j0 + 2) * 128,
        Y1, Y2, freq ? nullptr : (void*)((char*)Y2 + (size_t)TEN_ELEMS * 2),
        freq);

    hipMemsetAsync(SR, 0, 2 * 131072 * sizeof(float), stream);
    score_mfma<<<dim3(8, 32, 2), 256, 0, stream>>>(
        (const __bf16*)Y0, (const __bf16*)Y1, SR, SI);
    softmax_kernel<<<512, 256, 0, stream>>>(SR, SI, AM);

    const __bf16* VTh;
    const __bf16* VTl;
    if (!freq) {
      VTh = (const __bf16*)Y2;
      VTl = (const __bf16*)((char*)Y2 + (size_t)TEN_ELEMS * 2);
    } else {
      vt_transpose<<<dim3(16, 256), 256, 0, stream>>>(
          Y2, (__bf16*)Y0, (__bf16*)((char*)Y0 + (size_t)TEN_ELEMS * 2));
      VTh = (const __bf16*)Y0;
      VTl = (const __bf16*)((char*)Y0 + (size_t)TEN_ELEMS * 2);
    }
    av_mfma<<<dim3(128, 4, 4), 256, 0, stream>>>(AM, VTh, VTl, out, freq);
  }
}